// Round 5
// baseline (185.458 us; speedup 1.0000x reference)
//
#include <hip/hip_runtime.h>
#include <hip/hip_bf16.h>
#include <math.h>

#define NCAP 10
#define DCAP 16
#define DIN  128
#define NPOS 4096
#define NB   64
#define ROWS 64            // positions per tile
#define F4PRP 33           // padded float4-per-row (32 data + 1 pad)

// ---------------------------------------------------------------------------
// ws layout (floats):
//   partial : [64][16][128]      @ 0        (caps_sum chunk partials)
//   wbuf    : [64][10][128]      @ 131072   (w = W_n @ v per (b,n))
//   pws     : [64][64][10][128]  @ 212992   (per-tile partial c*u sums, 21 MB)
// Every ws element is written before read -> no memset, no atomics.
// ---------------------------------------------------------------------------

// Pass A: per-batch column sum of u (coalesced, two-level).
__global__ __launch_bounds__(256) void caps_sum(const float* __restrict__ u,
                                                float* __restrict__ partial) {
    const int b = blockIdx.x;
    const int chunk = blockIdx.y;          // 16 chunks of 256 positions
    const int t = threadIdx.x;
    const int v4 = t & 31;
    const int prow = t >> 5;
    const float4* up = (const float4*)u;
    const size_t posbase = (size_t)b * NPOS + chunk * 256;

    float4 acc = make_float4(0.f, 0.f, 0.f, 0.f);
    for (int j = 0; j < 32; ++j) {
        float4 x = up[(posbase + prow + j * 8) * 32 + v4];
        acc.x += x.x; acc.y += x.y; acc.z += x.z; acc.w += x.w;
    }
    __shared__ float4 red[8][32];
    red[prow][v4] = acc;
    __syncthreads();
    if (t < 32) {
        float4 s = red[0][t];
        for (int r = 1; r < 8; ++r) {
            s.x += red[r][t].x; s.y += red[r][t].y;
            s.z += red[r][t].z; s.w += red[r][t].w;
        }
        ((float4*)partial)[((size_t)b * 16 + chunk) * 32 + t] = s;
    }
}

// Small per-(b,n): reduce chunk partials -> s -> squash -> v -> w (or out).
// MODE 0: src = partial [64][16][128] (scale 0.1), dst = wbuf
// MODE 1: src = pws [64][64][10][128],             dst = wbuf
// MODE 2: src = pws,                               dst = out [64][10][16]
template <int MODE>
__global__ __launch_bounds__(128) void caps_small(const float* __restrict__ src,
                                                  const float* __restrict__ W,
                                                  float* __restrict__ dst) {
    const int b = blockIdx.x / NCAP;
    const int n = blockIdx.x % NCAP;
    const int t = threadIdx.x;             // 128 threads == din index

    __shared__ float xv[DIN];
    __shared__ float vv[DCAP];

    float a = 0.f;
    if (MODE == 0) {
        #pragma unroll 4
        for (int c = 0; c < 16; ++c)
            a += src[(size_t)(b * 16 + c) * DIN + t];
    } else {
        #pragma unroll 8
        for (int c = 0; c < 64; ++c)
            a += src[((size_t)(b * 64 + c) * NCAP + n) * DIN + t];
    }
    xv[t] = a;
    __syncthreads();

    if (t < DCAP) {
        float sv = 0.f;
        for (int d = 0; d < DIN; ++d)
            sv = fmaf(xv[d], W[d * (NCAP * DCAP) + n * DCAP + t], sv);
        if (MODE == 0) sv *= 0.1f;         // softmax of zeros over 10 capsules
        float nq = sv * sv;
        #pragma unroll
        for (int mm = 8; mm >= 1; mm >>= 1) nq += __shfl_xor(nq, mm, 16);
        nq += 1e-7f;
        const float coeff = sqrtf(nq) / (1.0f + nq);
        const float v = coeff * sv;
        if (MODE == 2)
            dst[(size_t)(b * NCAP + n) * DCAP + t] = v;
        else
            vv[t] = v;
    }
    if (MODE != 2) {
        __syncthreads();
        float wd = 0.f;
        #pragma unroll
        for (int dd = 0; dd < DCAP; ++dd)
            wd = fmaf(W[t * (NCAP * DCAP) + n * DCAP + dd], vv[dd], wd);
        dst[(size_t)(b * NCAP + n) * DIN + t] = wd;
    }
}

// Routing pass, LDS-staged. Block = 128 thr (2 waves), one 64-pos tile.
//  stage : coalesced 16B/lane global -> padded LDS [64][33] float4
//  p1    : lane==pos, wave w handles dim-half [w*64,(w+1)*64); W via s_load;
//          halves combined through small LDS logits buffer; softmax per lane.
//  p2    : wave w owns dims d=w*64+lane; readlane-broadcast of c; per-tile
//          partial written straight to pws (no atomics).
__global__ __launch_bounds__(128) void caps_route(const float* __restrict__ u,
                                                  const float* __restrict__ wsrc,
                                                  float* __restrict__ pdst) {
    const int b = blockIdx.x;
    const int tile = blockIdx.y;           // 64 tiles of 64 positions
    const int t = threadIdx.x;
    const int lane = t & 63;
    const int wS = __builtin_amdgcn_readfirstlane(t >> 6);  // wave id, SGPR

    __shared__ float4 tl[ROWS * F4PRP];    // 33792 B, padded
    __shared__ float lgp[2][ROWS][NCAP];   // 5120 B
    float* tlf = (float*)tl;

    // ---- stage: 2048 float4, linear->padded (bank-conflict-free) ----
    const float4* src = (const float4*)u + ((size_t)b * NPOS + tile * ROWS) * (DIN / 4);
    const int base = t + (t >> 5);         // r*33+j for linear idx t (+132/iter)
    #pragma unroll
    for (int i = 0; i < 16; ++i)
        tl[base + i * 132] = src[t + i * 128];
    __syncthreads();

    // ---- phase 1: partial logits over this wave's dim-half ----
    const float4* rowp = tl + lane * F4PRP + wS * 16;
    const float4* wb4 = (const float4*)(wsrc + (size_t)b * (NCAP * DIN)) + wS * 16;

    float lg[NCAP];
    #pragma unroll
    for (int n = 0; n < NCAP; ++n) lg[n] = 0.f;
    #pragma unroll 4
    for (int j = 0; j < 16; ++j) {
        const float4 u4 = rowp[j];
        #pragma unroll
        for (int n = 0; n < NCAP; ++n) {
            const float4 w4 = wb4[n * 32 + j];   // wave-uniform -> s_load
            lg[n] = fmaf(u4.x, w4.x, fmaf(u4.y, w4.y,
                    fmaf(u4.z, w4.z, fmaf(u4.w, w4.w, lg[n]))));
        }
    }
    #pragma unroll
    for (int n = 0; n < NCAP; ++n) lgp[wS][lane][n] = lg[n];
    __syncthreads();

    // combine halves + softmax (computed redundantly in both waves)
    float c[NCAP];
    float m = -1e30f;
    #pragma unroll
    for (int n = 0; n < NCAP; ++n) {
        c[n] = lgp[0][lane][n] + lgp[1][lane][n];
        m = fmaxf(m, c[n]);
    }
    float ssum = 0.f;
    #pragma unroll
    for (int n = 0; n < NCAP; ++n) { c[n] = __expf(c[n] - m); ssum += c[n]; }
    const float inv = 1.0f / ssum;
    #pragma unroll
    for (int n = 0; n < NCAP; ++n) c[n] *= inv;

    // ---- phase 2: wave w accumulates its dim d = w*64+lane over 64 pos ----
    float acc[NCAP];
    #pragma unroll
    for (int n = 0; n < NCAP; ++n) acc[n] = 0.f;
    const int fbase = wS * 64 + lane;      // float offset within padded row
    for (int p = 0; p < ROWS; ++p) {
        const float u0 = tlf[p * (4 * F4PRP) + fbase];
        #pragma unroll
        for (int n = 0; n < NCAP; ++n) {
            const float cp = __int_as_float(
                __builtin_amdgcn_readlane(__float_as_int(c[n]), p));
            acc[n] = fmaf(cp, u0, acc[n]);
        }
    }

    // ---- per-tile partial out (coalesced) ----
    float* pb = pdst + ((size_t)(b * 64 + tile) * NCAP) * DIN;
    #pragma unroll
    for (int n = 0; n < NCAP; ++n)
        pb[n * DIN + wS * 64 + lane] = acc[n];
}

extern "C" void kernel_launch(void* const* d_in, const int* in_sizes, int n_in,
                              void* d_out, int out_size, void* d_ws, size_t ws_size,
                              hipStream_t stream) {
    const float* u = (const float*)d_in[0];   // [64][4096][128]
    const float* W = (const float*)d_in[1];   // [128][160]
    float* out = (float*)d_out;               // [64][10][16]
    float* ws = (float*)d_ws;

    float* partial = ws;                      // 131072 floats
    float* wbuf    = ws + 131072;             // 81920 floats
    float* pws     = ws + 212992;             // 5242880 floats (21 MB)

    caps_sum<<<dim3(NB, 16), 256, 0, stream>>>(u, partial);
    caps_small<0><<<NB * NCAP, 128, 0, stream>>>(partial, W, wbuf);   // v1 -> w1
    caps_route<<<dim3(NB, 64), 128, 0, stream>>>(u, wbuf, pws);       // iter 2
    caps_small<1><<<NB * NCAP, 128, 0, stream>>>(pws, W, wbuf);       // v2 -> w2
    caps_route<<<dim3(NB, 64), 128, 0, stream>>>(u, wbuf, pws);       // iter 3
    caps_small<2><<<NB * NCAP, 128, 0, stream>>>(pws, W, out);        // v3 -> out
}

// Round 7
// 146.788 us; speedup vs baseline: 1.2634x; 1.2634x over previous
//
#include <hip/hip_runtime.h>
#include <hip/hip_bf16.h>
#include <math.h>

#define NCAP 10
#define DCAP 16
#define DIN  128
#define NPOS 4096
#define NB   64

// ---------------------------------------------------------------------------
// ws layout (floats):
//   partial : [64][16][128]      @ 0        (caps_sum chunk partials)
//   wbuf    : [64][10][128]      @ 131072   (w = W_n @ v per (b,n))
//   pws     : [64][16][10][128]  @ 212992   (per-256-pos partial c*u sums, 5.25 MB)
// Every ws element is written before read -> no memset, no atomics.
// ---------------------------------------------------------------------------

// Pass A: per-batch column sum of u (coalesced, two-level).
__global__ __launch_bounds__(256) void caps_sum(const float* __restrict__ u,
                                                float* __restrict__ partial) {
    const int b = blockIdx.x;
    const int chunk = blockIdx.y;          // 16 chunks of 256 positions
    const int t = threadIdx.x;
    const int v4 = t & 31;
    const int prow = t >> 5;
    const float4* up = (const float4*)u;
    const size_t posbase = (size_t)b * NPOS + chunk * 256;

    float4 acc = make_float4(0.f, 0.f, 0.f, 0.f);
    #pragma unroll 8
    for (int j = 0; j < 32; ++j) {
        float4 x = up[(posbase + prow + j * 8) * 32 + v4];
        acc.x += x.x; acc.y += x.y; acc.z += x.z; acc.w += x.w;
    }
    __shared__ float4 red[8][32];
    red[prow][v4] = acc;
    __syncthreads();
    if (t < 32) {
        float4 s = red[0][t];
        #pragma unroll
        for (int r = 1; r < 8; ++r) {
            s.x += red[r][t].x; s.y += red[r][t].y;
            s.z += red[r][t].z; s.w += red[r][t].w;
        }
        ((float4*)partial)[((size_t)b * 16 + chunk) * 32 + t] = s;
    }
}

// Small per-(b,n): reduce chunk partials -> s -> squash -> v -> w (or out).
// MODE 0: src = partial [64][16][128] (scale 0.1), dst = wbuf
// MODE 1: src = pws [64][16][10][128],             dst = wbuf
// MODE 2: src = pws,                               dst = out [64][10][16]
template <int MODE>
__global__ __launch_bounds__(128) void caps_small(const float* __restrict__ src,
                                                  const float* __restrict__ W,
                                                  float* __restrict__ dst) {
    const int b = blockIdx.x / NCAP;
    const int n = blockIdx.x % NCAP;
    const int t = threadIdx.x;             // 128 threads == din index

    __shared__ float xv[DIN];
    __shared__ float vv[DCAP];

    float a = 0.f;
    if (MODE == 0) {
        #pragma unroll 4
        for (int c = 0; c < 16; ++c)
            a += src[(size_t)(b * 16 + c) * DIN + t];
    } else {
        #pragma unroll 4
        for (int c = 0; c < 16; ++c)
            a += src[((size_t)(b * 16 + c) * NCAP + n) * DIN + t];
    }
    xv[t] = a;
    __syncthreads();

    if (t < DCAP) {
        float sv = 0.f;
        for (int d = 0; d < DIN; ++d)
            sv = fmaf(xv[d], W[d * (NCAP * DCAP) + n * DCAP + t], sv);
        if (MODE == 0) sv *= 0.1f;         // softmax of zeros over 10 capsules
        float nq = sv * sv;
        #pragma unroll
        for (int mm = 8; mm >= 1; mm >>= 1) nq += __shfl_xor(nq, mm, 16);
        nq += 1e-7f;
        const float coeff = sqrtf(nq) / (1.0f + nq);
        const float v = coeff * sv;
        if (MODE == 2)
            dst[(size_t)(b * NCAP + n) * DCAP + t] = v;
        else
            vv[t] = v;
    }
    if (MODE != 2) {
        __syncthreads();
        float wd = 0.f;
        #pragma unroll
        for (int dd = 0; dd < DCAP; ++dd)
            wd = fmaf(W[t * (NCAP * DCAP) + n * DCAP + dd], vv[dd], wd);
        dst[(size_t)(b * NCAP + n) * DIN + t] = wd;
    }
}

// Routing pass. Block = 256 thr (4 waves) owns 256 positions, processed as
// four 64-pos subtiles through one XOR-swizzled LDS tile (32 KB):
//   stage : coalesced; f4 (r,c) stored at col c^(r&7)  -> all phases bank-clean
//   p1    : wave w = dim-quarter (W wave-uniform -> s_load); lane = position;
//           partial logits through lgp[4][64][11]; softmax redundant per wave
//   p2    : wave w = position-quarter; lane = dims {l, l+64}; c via v_readlane;
//           acc held in registers across all 4 subtiles
//   fold  : cross-wave sum via LDS (tile reused), one coalesced partial store.
__global__ __launch_bounds__(256, 3) void caps_route(const float* __restrict__ u,
                                                     const float* __restrict__ wsrc,
                                                     float* __restrict__ pdst) {
    const int b = blockIdx.x;
    const int tile = blockIdx.y;           // 16 tiles of 256 positions
    const int t = threadIdx.x;
    const int lane = t & 63;
    const int wv = __builtin_amdgcn_readfirstlane(t >> 6);  // wave id, SGPR

    __shared__ float4 tl4[64 * 32];        // 32768 B, swizzled
    __shared__ float lgp[4][64][11];       // 11264 B, pad 11 -> conflict-free
    float* tlf = (float*)tl4;

    const float4* wq4 = (const float4*)(wsrc + (size_t)b * (NCAP * DIN));

    float acc0[NCAP], acc1[NCAP];          // dims lane, lane+64; persist
    #pragma unroll
    for (int n = 0; n < NCAP; ++n) { acc0[n] = 0.f; acc1[n] = 0.f; }

    for (int s = 0; s < 4; ++s) {
        __syncthreads();                   // tile safe to overwrite
        // ---- stage 64 pos x 128 dims, swizzled ----
        const float4* src4 = (const float4*)u +
            ((size_t)b * NPOS + tile * 256 + s * 64) * 32;
        #pragma unroll
        for (int i = 0; i < 8; ++i) {
            const int q = t + i * 256;
            const int r = q >> 5, c = q & 31;
            tl4[r * 32 + (c ^ (r & 7))] = src4[q];
        }
        __syncthreads();

        // ---- p1: wave wv handles dims [wv*32, wv*32+32), lane = pos ----
        float lg[NCAP];
        #pragma unroll
        for (int n = 0; n < NCAP; ++n) lg[n] = 0.f;
        #pragma unroll
        for (int j = 0; j < 8; ++j) {
            const float4 u4 = tl4[lane * 32 + wv * 8 + (j ^ (lane & 7))];
            #pragma unroll
            for (int n = 0; n < NCAP; ++n) {
                const float4 w4 = wq4[n * 32 + wv * 8 + j];   // uniform -> s_load
                lg[n] = fmaf(u4.x, w4.x, fmaf(u4.y, w4.y,
                        fmaf(u4.z, w4.z, fmaf(u4.w, w4.w, lg[n]))));
            }
        }
        #pragma unroll
        for (int n = 0; n < NCAP; ++n) lgp[wv][lane][n] = lg[n];
        __syncthreads();

        // ---- combine quarters + softmax (per lane = pos; all waves) ----
        float c[NCAP];
        float m = -1e30f;
        #pragma unroll
        for (int n = 0; n < NCAP; ++n) {
            c[n] = lgp[0][lane][n] + lgp[1][lane][n] +
                   lgp[2][lane][n] + lgp[3][lane][n];
            m = fmaxf(m, c[n]);
        }
        float ssum = 0.f;
        #pragma unroll
        for (int n = 0; n < NCAP; ++n) { c[n] = __expf(c[n] - m); ssum += c[n]; }
        const float inv = 1.0f / ssum;
        #pragma unroll
        for (int n = 0; n < NCAP; ++n) c[n] *= inv;

        // ---- p2: wave wv accumulates positions [wv*16, wv*16+16) ----
        const int col0 = lane >> 2, word = lane & 3;
        #pragma unroll
        for (int i = 0; i < 16; ++i) {
            const int p = wv * 16 + i;
            const int ca = col0 ^ (p & 7);
            const float u0 = tlf[(p * 32 + ca) * 4 + word];
            const float u1 = tlf[(p * 32 + ca + 16) * 4 + word];
            #pragma unroll
            for (int n = 0; n < NCAP; ++n) {
                const float cp = __int_as_float(
                    __builtin_amdgcn_readlane(__float_as_int(c[n]), p));
                acc0[n] = fmaf(cp, u0, acc0[n]);
                acc1[n] = fmaf(cp, u1, acc1[n]);
            }
        }
    }

    // ---- fold 4 per-wave partials, store one partial per block ----
    __syncthreads();                       // p2 reads done; reuse tile as red
    float* red = tlf;                      // [4][10][128] = 20 KB
    #pragma unroll
    for (int n = 0; n < NCAP; ++n) {
        red[(wv * NCAP + n) * DIN + lane]      = acc0[n];
        red[(wv * NCAP + n) * DIN + lane + 64] = acc1[n];
    }
    __syncthreads();
    float* pb = pdst + (size_t)(b * 16 + tile) * (NCAP * DIN);
    for (int k = t; k < NCAP * DIN; k += 256) {
        pb[k] = red[k] + red[1280 + k] + red[2560 + k] + red[3840 + k];
    }
}

extern "C" void kernel_launch(void* const* d_in, const int* in_sizes, int n_in,
                              void* d_out, int out_size, void* d_ws, size_t ws_size,
                              hipStream_t stream) {
    const float* u = (const float*)d_in[0];   // [64][4096][128]
    const float* W = (const float*)d_in[1];   // [128][160]
    float* out = (float*)d_out;               // [64][10][16]
    float* ws = (float*)d_ws;

    float* partial = ws;                      // 131072 floats
    float* wbuf    = ws + 131072;             // 81920 floats
    float* pws     = ws + 212992;             // 1310720 floats (5.25 MB)

    caps_sum<<<dim3(NB, 16), 256, 0, stream>>>(u, partial);
    caps_small<0><<<NB * NCAP, 128, 0, stream>>>(partial, W, wbuf);   // v1 -> w1
    caps_route<<<dim3(NB, 16), 256, 0, stream>>>(u, wbuf, pws);       // iter 2
    caps_small<1><<<NB * NCAP, 128, 0, stream>>>(pws, W, wbuf);       // v2 -> w2
    caps_route<<<dim3(NB, 16), 256, 0, stream>>>(u, wbuf, pws);       // iter 3
    caps_small<2><<<NB * NCAP, 128, 0, stream>>>(pws, W, out);        // v3 -> out
}